// Round 1
// baseline (5881.207 us; speedup 1.0000x reference)
//
#include <hip/hip_runtime.h>
#include <hip/hip_bf16.h>
#include <stdint.h>

#define B_  64
#define T_  256
#define E_  1024
#define UN  1024
#define KIN 2048     // E_+UN
#define N3  3072     // 3*UN
#define M_  16384    // B_*T_

typedef __attribute__((ext_vector_type(8))) short short8;
typedef __attribute__((ext_vector_type(4))) float f32x4;

static __device__ __forceinline__ float bf2f(short s) {
    union { float f; uint32_t u; } c; c.u = ((uint32_t)(uint16_t)s) << 16; return c.f;
}
static __device__ __forceinline__ short f2bf(float f) {
    union { float f; uint32_t u; } c; c.f = f;
    uint32_t u = c.u;
    uint32_t r = (u + 0x7fffu + ((u >> 16) & 1u)) >> 16;   // round-nearest-even
    return (short)(uint16_t)r;
}

// ---------------- prep: weights -> bf16 transposed layouts ----------------
// WcatT[n][k]  (N3 x KIN):  n<1024:r  1024..2047:z  2048..3071:c ; k<1024: C_* ; k>=1024: W_*
// UcatT[n][k]  (2048 x 1024): n<1024: U_r ; else U_z
// UcT[n][k]    (1024 x 1024): U
__global__ __launch_bounds__(256)
void k_prep_w(const float* __restrict__ Wr, const float* __restrict__ Ur, const float* __restrict__ Cr,
              const float* __restrict__ Wz, const float* __restrict__ Uz, const float* __restrict__ Cz,
              const float* __restrict__ Wc, const float* __restrict__ Uc, const float* __restrict__ Cc,
              short* __restrict__ WcatT, short* __restrict__ UcatT, short* __restrict__ UcT)
{
    __shared__ float tile[32][33];
    int m = blockIdx.z;
    const float* src; short* dst; int ld, noff, koff;
    switch (m) {
      case 0: src=Cr; dst=WcatT; ld=KIN;  noff=0;    koff=0;    break;
      case 1: src=Wr; dst=WcatT; ld=KIN;  noff=0;    koff=1024; break;
      case 2: src=Cz; dst=WcatT; ld=KIN;  noff=1024; koff=0;    break;
      case 3: src=Wz; dst=WcatT; ld=KIN;  noff=1024; koff=1024; break;
      case 4: src=Cc; dst=WcatT; ld=KIN;  noff=2048; koff=0;    break;
      case 5: src=Wc; dst=WcatT; ld=KIN;  noff=2048; koff=1024; break;
      case 6: src=Ur; dst=UcatT; ld=1024; noff=0;    koff=0;    break;
      case 7: src=Uz; dst=UcatT; ld=1024; noff=1024; koff=0;    break;
      default: src=Uc; dst=UcT;  ld=1024; noff=0;    koff=0;    break;
    }
    int n0 = blockIdx.x * 32, k0 = blockIdx.y * 32;
    int tx = threadIdx.x, ty = threadIdx.y;      // block (32,8)
    #pragma unroll
    for (int i = 0; i < 32; i += 8)
        tile[ty + i][tx] = src[(long)(k0 + ty + i) * 1024 + (n0 + tx)];
    __syncthreads();
    #pragma unroll
    for (int i = 0; i < 32; i += 8)
        dst[(long)(noff + n0 + ty + i) * ld + koff + k0 + tx] = f2bf(tile[tx][ty + i]);
}

// ---------------- prep: X -> bf16 ----------------
__global__ __launch_bounds__(256)
void k_prep_x(const float* __restrict__ X, short* __restrict__ Xb, long n8)
{
    long i = (long)blockIdx.x * blockDim.x + threadIdx.x;
    long stride = (long)gridDim.x * blockDim.x;
    for (; i < n8; i += stride) {
        const float4* p = (const float4*)(X + i * 8);
        float4 a = p[0], b = p[1];
        short8 o;
        o[0]=f2bf(a.x); o[1]=f2bf(a.y); o[2]=f2bf(a.z); o[3]=f2bf(a.w);
        o[4]=f2bf(b.x); o[5]=f2bf(b.y); o[6]=f2bf(b.z); o[7]=f2bf(b.w);
        *(short8*)(Xb + i * 8) = o;
    }
}

__global__ __launch_bounds__(256)
void k_init_h(const float* __restrict__ h0, float* __restrict__ h, short* __restrict__ hb)
{
    int i = blockIdx.x * 256 + threadIdx.x;   // 256 blocks -> 65536
    float v = h0[i];
    h[i] = v; hb[i] = f2bf(v);
}

// ---------------- phase 1: P = Xb @ Wcat  (M=16384, N=3072, K=2048), P bf16 ----------------
__global__ __launch_bounds__(256)
void k_gemm_x(const short* __restrict__ Xb, const short* __restrict__ WcatT, short* __restrict__ P)
{
    __shared__ short As[128 * 64];
    __shared__ short Bs[128 * 64];
    int tid = threadIdx.x;
    int lane = tid & 63, wave = tid >> 6;
    int i0 = blockIdx.y * 128;    // M block
    int n0 = blockIdx.x * 128;    // N block
    int wrow = (wave >> 1) * 64, wcol = (wave & 1) * 64;
    f32x4 acc[4][4] = {};

    for (int k0 = 0; k0 < KIN; k0 += 64) {
        __syncthreads();
        #pragma unroll
        for (int j = 0; j < 4; j++) {
            int e = (j * 256 + tid) * 8;
            int row = e >> 6, k = e & 63;
            short8 va = *(const short8*)(Xb    + (long)(i0 + row) * KIN + k0 + k);
            short8 vb = *(const short8*)(WcatT + (long)(n0 + row) * KIN + k0 + k);
            int byt = row * 128 + ((k * 2) ^ ((row & 7) << 4));   // XOR swizzle
            *(short8*)((char*)As + byt) = va;
            *(short8*)((char*)Bs + byt) = vb;
        }
        __syncthreads();
        #pragma unroll
        for (int kk = 0; kk < 64; kk += 32) {
            short8 af[4], bfr[4];
            int kel = kk + (lane >> 4) * 8;
            #pragma unroll
            for (int rt = 0; rt < 4; rt++) {
                int row = wrow + rt * 16 + (lane & 15);
                int byt = row * 128 + ((kel * 2) ^ ((row & 7) << 4));
                af[rt] = *(const short8*)((const char*)As + byt);
            }
            #pragma unroll
            for (int ct = 0; ct < 4; ct++) {
                int row = wcol + ct * 16 + (lane & 15);
                int byt = row * 128 + ((kel * 2) ^ ((row & 7) << 4));
                bfr[ct] = *(const short8*)((const char*)Bs + byt);
            }
            #pragma unroll
            for (int rt = 0; rt < 4; rt++)
                #pragma unroll
                for (int ct = 0; ct < 4; ct++)
                    acc[rt][ct] = __builtin_amdgcn_mfma_f32_16x16x32_bf16(af[rt], bfr[ct], acc[rt][ct], 0, 0, 0);
        }
    }
    #pragma unroll
    for (int rt = 0; rt < 4; rt++)
      #pragma unroll
      for (int ct = 0; ct < 4; ct++)
        #pragma unroll
        for (int r = 0; r < 4; r++) {
            int row = i0 + wrow + rt * 16 + (lane >> 4) * 4 + r;
            int col = n0 + wcol + ct * 16 + (lane & 15);
            P[(long)row * N3 + col] = f2bf(acc[rt][ct][r]);
        }
}

// ---------------- per-step phase A: rz = hardsig(P_rz[t] + h @ Ucat) ----------------
// grid 128 blocks x 256 thr : 512 waves, wave -> 16x16 tile of (64 x 2048)
__global__ __launch_bounds__(256)
void k_stepA(const short* __restrict__ hb, const short* __restrict__ UcatT,
             const short* __restrict__ P, const float* __restrict__ h,
             short* __restrict__ rh, float* __restrict__ zbuf, int t)
{
    int lane = threadIdx.x & 63, wave = threadIdx.x >> 6;
    int wid = blockIdx.x * 4 + wave;      // 0..511
    int ct = wid & 127, rt = wid >> 7;
    int r0 = rt * 16, n0 = ct * 16;
    int lrow = lane & 15, lk = (lane >> 4) * 8;
    f32x4 acc = {0.f, 0.f, 0.f, 0.f};
    const short8* Aptr = (const short8*)(hb    + (r0 + lrow) * 1024 + lk);
    const short8* Bptr = (const short8*)(UcatT + (n0 + lrow) * 1024 + lk);
    #pragma unroll 8
    for (int kk = 0; kk < 32; kk++)
        acc = __builtin_amdgcn_mfma_f32_16x16x32_bf16(Aptr[kk * 4], Bptr[kk * 4], acc, 0, 0, 0);

    int col = n0 + (lane & 15);
    int brb = r0 + (lane >> 4) * 4;
    #pragma unroll
    for (int r = 0; r < 4; r++) {
        int b = brb + r;
        float pre = acc[r] + bf2f(P[(long)(b * T_ + t) * N3 + col]);
        float v = fminf(fmaxf(0.2f * pre + 0.5f, 0.f), 1.f);
        if (col < 1024)
            rh[b * 1024 + col] = f2bf(v * h[b * 1024 + col]);
        else
            zbuf[b * 1024 + (col - 1024)] = v;
    }
}

// ---------------- per-step phase B: hc = tanh(P_c[t] + (h.r) @ U); h = lerp ----------------
// grid 64 blocks x 256 thr : 256 waves, wave -> 16x16 tile of (64 x 1024)
__global__ __launch_bounds__(256)
void k_stepB(const short* __restrict__ rh, const short* __restrict__ UcT,
             const short* __restrict__ P, const float* __restrict__ zbuf,
             float* __restrict__ h, short* __restrict__ hb,
             float* __restrict__ out, int t)
{
    int lane = threadIdx.x & 63, wave = threadIdx.x >> 6;
    int wid = blockIdx.x * 4 + wave;      // 0..255
    int ct = wid & 63, rt = wid >> 6;
    int r0 = rt * 16, n0 = ct * 16;
    int lrow = lane & 15, lk = (lane >> 4) * 8;
    f32x4 acc = {0.f, 0.f, 0.f, 0.f};
    const short8* Aptr = (const short8*)(rh  + (r0 + lrow) * 1024 + lk);
    const short8* Bptr = (const short8*)(UcT + (n0 + lrow) * 1024 + lk);
    #pragma unroll 8
    for (int kk = 0; kk < 32; kk++)
        acc = __builtin_amdgcn_mfma_f32_16x16x32_bf16(Aptr[kk * 4], Bptr[kk * 4], acc, 0, 0, 0);

    int col = n0 + (lane & 15);
    int brb = r0 + (lane >> 4) * 4;
    #pragma unroll
    for (int r = 0; r < 4; r++) {
        int b = brb + r;
        float pre = acc[r] + bf2f(P[(long)(b * T_ + t) * N3 + 2048 + col]);
        float hc = tanhf(pre);
        float z  = zbuf[b * 1024 + col];
        float ho = h[b * 1024 + col];
        float hn = (1.f - z) * ho + z * hc;
        h[b * 1024 + col]  = hn;
        hb[b * 1024 + col] = f2bf(hn);
        out[(long)(b * T_ + t) * 1024 + col] = hn;
    }
}

extern "C" void kernel_launch(void* const* d_in, const int* in_sizes, int n_in,
                              void* d_out, int out_size, void* d_ws, size_t ws_size,
                              hipStream_t stream)
{
    (void)in_sizes; (void)n_in; (void)out_size; (void)ws_size;
    const float* X   = (const float*)d_in[0];
    const float* h0  = (const float*)d_in[1];
    const float* W_r = (const float*)d_in[2];
    const float* U_r = (const float*)d_in[3];
    const float* C_r = (const float*)d_in[4];
    const float* W_z = (const float*)d_in[5];
    const float* U_z = (const float*)d_in[6];
    const float* C_z = (const float*)d_in[7];
    const float* W   = (const float*)d_in[8];
    const float* U   = (const float*)d_in[9];
    const float* C   = (const float*)d_in[10];

    char* ws = (char*)d_ws;
    size_t off = 0;
    short* WcatT = (short*)(ws + off); off += (size_t)N3 * KIN * 2;      // 12,582,912
    short* UcatT = (short*)(ws + off); off += (size_t)2048 * 1024 * 2;   //  4,194,304
    short* UcT   = (short*)(ws + off); off += (size_t)1024 * 1024 * 2;   //  2,097,152
    short* Xb    = (short*)(ws + off); off += (size_t)M_ * KIN * 2;      // 67,108,864
    short* P     = (short*)(ws + off); off += (size_t)M_ * N3 * 2;       // 100,663,296
    float* h     = (float*)(ws + off); off += (size_t)B_ * UN * 4;
    short* hb    = (short*)(ws + off); off += (size_t)B_ * UN * 2;
    short* rh    = (short*)(ws + off); off += (size_t)B_ * UN * 2;
    float* zbuf  = (float*)(ws + off); off += (size_t)B_ * UN * 4;
    // total ~187.4 MB

    k_prep_w<<<dim3(32, 32, 9), dim3(32, 8), 0, stream>>>(W_r, U_r, C_r, W_z, U_z, C_z, W, U, C,
                                                          WcatT, UcatT, UcT);
    k_prep_x<<<2048, 256, 0, stream>>>(X, Xb, (long)M_ * KIN / 8);
    k_init_h<<<256, 256, 0, stream>>>(h0, h, hb);
    k_gemm_x<<<dim3(N3 / 128, M_ / 128), 256, 0, stream>>>(Xb, WcatT, P);

    float* out = (float*)d_out;
    for (int t = 0; t < T_; t++) {
        k_stepA<<<128, 256, 0, stream>>>(hb, UcatT, P, h, rh, zbuf, t);
        k_stepB<<<64, 256, 0, stream>>>(rh, UcT, P, zbuf, h, hb, out, t);
    }
}